// Round 2
// baseline (2544.749 us; speedup 1.0000x reference)
//
#include <hip/hip_runtime.h>

#define B_ 2
#define N_ 512
#define E_ 64
#define LIN_IN_ 192

// ---------------- t1/t2 precompute: t1[b,n,e] = h[b,n,:]·W_lin[e, 0:64],
//                  t2[b,n,e] = h[b,n,:]·W_lin[e, 128:192] ----------------
__global__ __launch_bounds__(64) void tkernel(const float* __restrict__ h,
                                              const float* __restrict__ Wlin,
                                              float* __restrict__ t1,
                                              float* __restrict__ t2) {
  int row = blockIdx.x;      // b*N + n
  int e = threadIdx.x;       // 0..63
  const float* hrow = h + (size_t)row * E_;          // uniform across block -> s_load
  const float* w = Wlin + (size_t)e * LIN_IN_;
  float a1 = 0.f, a2 = 0.f;
#pragma unroll
  for (int f = 0; f < E_; ++f) {
    float hv = hrow[f];
    a1 += hv * w[f];
    a2 += hv * w[128 + f];
  }
  t1[(size_t)row * E_ + e] = a1;
  t2[(size_t)row * E_ + e] = a2;
}

// ---------------- pass 1: m[b,i,j,e] = adj*(b_lin + t1[b,j] + t2[b,i] + edge·We^T)
// one thread per pair; m written into d_out (scratch). ----------------
template <bool USE_T>
__global__ __launch_bounds__(64) void mkernel(const float* __restrict__ edge,
                                              const float* __restrict__ adj,
                                              const float* __restrict__ Wlin,
                                              const float* __restrict__ blin,
                                              const float* __restrict__ t1,
                                              const float* __restrict__ t2,
                                              const float* __restrict__ h,
                                              float* __restrict__ mout) {
  size_t p = (size_t)blockIdx.x * 64 + threadIdx.x;   // 0 .. B*N*N-1
  int b = (int)(p >> 18);          // / (N*N) with N=512
  int i = (int)((p >> 9) & 511);
  int j = (int)(p & 511);

  float ed[E_];
  const float4* ep = (const float4*)(edge + p * E_);
#pragma unroll
  for (int k = 0; k < E_ / 4; ++k) {
    float4 v = ep[k];
    ed[4 * k] = v.x; ed[4 * k + 1] = v.y; ed[4 * k + 2] = v.z; ed[4 * k + 3] = v.w;
  }
  float av = adj[p];
  float* mo = mout + p * E_;

  if (USE_T) {
    const float* t1r = t1 + ((size_t)(b * N_ + j)) * E_;
    const float* t2r = t2 + ((size_t)(b * N_ + i)) * E_;
    for (int e = 0; e < E_; ++e) {
      const float* w = Wlin + e * LIN_IN_ + 64;       // We row e (uniform -> s_load)
      float acc = blin[e] + t1r[e] + t2r[e];
#pragma unroll
      for (int k = 0; k < E_; ++k) acc += ed[k] * w[k];
      mo[e] = av * acc;
    }
  } else {
    // fallback: recompute t1/t2 inline (no workspace dependence)
    float hj[E_], hi[E_];
    const float4* hjp = (const float4*)(h + ((size_t)(b * N_ + j)) * E_);
    const float4* hip = (const float4*)(h + ((size_t)(b * N_ + i)) * E_);
#pragma unroll
    for (int k = 0; k < E_ / 4; ++k) {
      float4 v = hjp[k];
      hj[4 * k] = v.x; hj[4 * k + 1] = v.y; hj[4 * k + 2] = v.z; hj[4 * k + 3] = v.w;
      float4 u = hip[k];
      hi[4 * k] = u.x; hi[4 * k + 1] = u.y; hi[4 * k + 2] = u.z; hi[4 * k + 3] = u.w;
    }
    for (int e = 0; e < E_; ++e) {
      const float* w = Wlin + e * LIN_IN_;
      float acc = blin[e];
#pragma unroll
      for (int k = 0; k < E_; ++k)
        acc += hj[k] * w[k] + ed[k] * w[64 + k] + hi[k] * w[128 + k];
      mo[e] = av * acc;
    }
  }
}

// ---------------- pass 2: GRU gates + output. Reads m from d_out, overwrites
// d_out in place (per-thread identical addresses, no cross-thread hazard).
// NOTE: mbuf and out intentionally NOT __restrict__ (they alias). ----------------
__global__ __launch_bounds__(64) void gkernel(const float* __restrict__ edge,
                                              const float* mbuf,
                                              const float* __restrict__ wih,
                                              const float* __restrict__ whh,
                                              const float* __restrict__ bih,
                                              const float* __restrict__ bhh,
                                              float* out) {
  size_t p = (size_t)blockIdx.x * 64 + threadIdx.x;
  float ed[E_], m[E_];
  const float4* ep = (const float4*)(edge + p * E_);
  const float4* mp = (const float4*)(mbuf + p * E_);
#pragma unroll
  for (int k = 0; k < E_ / 4; ++k) {
    float4 v = ep[k];
    ed[4 * k] = v.x; ed[4 * k + 1] = v.y; ed[4 * k + 2] = v.z; ed[4 * k + 3] = v.w;
    float4 u = mp[k];
    m[4 * k] = u.x; m[4 * k + 1] = u.y; m[4 * k + 2] = u.z; m[4 * k + 3] = u.w;
  }
  float* op = out + p * E_;
  for (int e = 0; e < E_; ++e) {
    const float* wr = wih + e * 64;            // uniform rows -> s_load
    const float* wz = wih + (64 + e) * 64;
    const float* wn = wih + (128 + e) * 64;
    const float* vr = whh + e * 64;
    const float* vz = whh + (64 + e) * 64;
    const float* vn = whh + (128 + e) * 64;
    float ir = bih[e], iz = bih[64 + e], inn = bih[128 + e];
    float hr = bhh[e], hz = bhh[64 + e], hn = bhh[128 + e];
#pragma unroll
    for (int k = 0; k < E_; ++k) {
      float mk = m[k], ek = ed[k];
      ir += mk * wr[k];
      iz += mk * wz[k];
      inn += mk * wn[k];
      hr += ek * vr[k];
      hz += ek * vz[k];
      hn += ek * vn[k];
    }
    float r = 1.f / (1.f + __expf(-(ir + hr)));
    float z = 1.f / (1.f + __expf(-(iz + hz)));
    float nv = tanhf(inn + r * hn);
    float nh = (1.f - z) * nv + z * ed[e];
    op[e] = nh / (1.f + __expf(-nh));          // silu
  }
}

extern "C" void kernel_launch(void* const* d_in, const int* in_sizes, int n_in,
                              void* d_out, int out_size, void* d_ws, size_t ws_size,
                              hipStream_t stream) {
  const float* h    = (const float*)d_in[0];
  const float* edge = (const float*)d_in[1];
  const float* adj  = (const float*)d_in[2];
  const float* Wlin = (const float*)d_in[3];
  const float* blin = (const float*)d_in[4];
  const float* wih  = (const float*)d_in[5];
  const float* whh  = (const float*)d_in[6];
  const float* bih  = (const float*)d_in[7];
  const float* bhh  = (const float*)d_in[8];
  float* out = (float*)d_out;

  size_t npairs = (size_t)B_ * N_ * N_;
  int blocks = (int)(npairs / 64);
  size_t tbytes = 2ull * B_ * N_ * E_ * sizeof(float);

  if (ws_size >= tbytes) {
    float* t1 = (float*)d_ws;
    float* t2 = t1 + (size_t)B_ * N_ * E_;
    tkernel<<<B_ * N_, 64, 0, stream>>>(h, Wlin, t1, t2);
    mkernel<true><<<blocks, 64, 0, stream>>>(edge, adj, Wlin, blin, t1, t2, h, out);
  } else {
    mkernel<false><<<blocks, 64, 0, stream>>>(edge, adj, Wlin, blin, nullptr, nullptr, h, out);
  }
  gkernel<<<blocks, 64, 0, stream>>>(edge, out, wih, whh, bih, bhh, out);
}

// Round 3
// 155.395 us; speedup vs baseline: 16.3760x; 16.3760x over previous
//
#include <hip/hip_runtime.h>

#define B_ 2
#define N_ 512
#define E_ 64
#define G_ 192
#define LIN_IN_ 192

typedef __attribute__((ext_vector_type(8))) short bf16x8;
typedef __attribute__((ext_vector_type(4))) float f32x4;

__device__ __forceinline__ unsigned short f2bf(float x) {
  unsigned u = __float_as_uint(x);
  unsigned r = (u + 0x7FFFu + ((u >> 16) & 1u)) >> 16;
  return (unsigned short)r;
}
__device__ __forceinline__ float sigm(float x) { return 1.f / (1.f + __expf(-x)); }
__device__ __forceinline__ float tanh_f(float x) {
  float e = __expf(-2.f * fabsf(x));
  return copysignf((1.f - e) / (1.f + e), x);
}

// ---------- prep1: W2e=wih·We (bf16 into Bt rows 0..191), Bt rows 192..383 = whh bf16,
//            V1=wih·W1, V2=wih·W2h, ub=wih·blin ----------
__global__ __launch_bounds__(64) void prep1(const float* __restrict__ Wlin,
                                            const float* __restrict__ blin,
                                            const float* __restrict__ wih,
                                            const float* __restrict__ whh,
                                            unsigned short* __restrict__ Bt,
                                            float* __restrict__ V1,
                                            float* __restrict__ V2,
                                            float* __restrict__ ub) {
  int g = blockIdx.x;   // 0..383
  int f = threadIdx.x;  // 0..63
  if (g < G_) {
    const float* wr = wih + g * 64;  // uniform -> s_load
    float aw = 0.f, a1 = 0.f, a2 = 0.f;
#pragma unroll
    for (int e = 0; e < 64; ++e) {
      float wv = wr[e];
      a1 += wv * Wlin[e * LIN_IN_ + f];
      aw += wv * Wlin[e * LIN_IN_ + 64 + f];
      a2 += wv * Wlin[e * LIN_IN_ + 128 + f];
    }
    Bt[g * 64 + f] = f2bf(aw);
    V1[g * 64 + f] = a1;
    V2[g * 64 + f] = a2;
    if (f == 0) {
      float s = 0.f;
      for (int e = 0; e < 64; ++e) s += wr[e] * blin[e];
      ub[g] = s;
    }
  } else {
    int gh = g - G_;
    Bt[g * 64 + f] = f2bf(whh[gh * 64 + f]);
  }
}

// ---------- prep2: u1[row,g]=V1[g,:]·h[row,:], u2[row,g]=V2[g,:]·h[row,:] ----------
__global__ __launch_bounds__(192) void prep2(const float* __restrict__ h,
                                             const float* __restrict__ V1,
                                             const float* __restrict__ V2,
                                             float* __restrict__ u1,
                                             float* __restrict__ u2) {
  int row = blockIdx.x;   // b*N+n
  int g = threadIdx.x;    // 0..191
  const float* hr = h + (size_t)row * 64;  // uniform
  float a1 = 0.f, a2 = 0.f;
#pragma unroll
  for (int f = 0; f < 64; ++f) {
    float hv = hr[f];
    a1 += V1[g * 64 + f] * hv;
    a2 += V2[g * 64 + f] * hv;
  }
  u1[(size_t)row * G_ + g] = a1;
  u2[(size_t)row * G_ + g] = a2;
}

// ---------- fused: lin[p,0:384] = edge[p,:]·Bt^T via MFMA, then gates ----------
// block: 256 thr (4 waves), each wave 64 pairs (4 m-tiles of 16). Grid covers
// 256 consecutive pairs per block -> (b,i) fixed per block, j varies.
__global__ __launch_bounds__(256, 2) void fused(const float* __restrict__ edge,
                                                const float* __restrict__ adj,
                                                const unsigned short* __restrict__ BtW,
                                                const float* __restrict__ u1,
                                                const float* __restrict__ u2,
                                                const float* __restrict__ ub,
                                                const float* __restrict__ bih,
                                                const float* __restrict__ bhh,
                                                float* __restrict__ out) {
  __shared__ uint4 BtL4[3072];  // 48 KB: Bt[384 rows][64 bf16], XOR-swizzled
  char* Bc = (char*)BtL4;
  int tid = threadIdx.x;
  const uint4* src = (const uint4*)BtW;
#pragma unroll
  for (int c = 0; c < 12; ++c) {
    int ch = tid + c * 256;          // 3072 chunks of 16B
    int row = ch >> 3, col = ch & 7;
    uint4 v = src[ch];
    *(uint4*)(Bc + row * 128 + ((col * 16) ^ ((row & 7) << 4))) = v;
  }
  __syncthreads();

  int lane = tid & 63, wave = tid >> 6;
  unsigned pbase = blockIdx.x * 256u + wave * 64u;
  int b = pbase >> 18;
  int i = (pbase >> 9) & 511;
  int j0 = pbase & 511;
  int lr = lane & 15, lg = lane >> 4;

  // A-fragments: lane holds row (lr) of each 16-pair m-tile, k = s*32+lg*8+j
  bf16x8 afrag[4][2];
#pragma unroll
  for (int mt = 0; mt < 4; ++mt) {
    const float* ep = edge + (size_t)(pbase + mt * 16 + lr) * 64 + lg * 8;
    float tmp[8];
    *(float4*)tmp = *(const float4*)ep;
    *(float4*)(tmp + 4) = *(const float4*)(ep + 4);
    bf16x8 v;
#pragma unroll
    for (int q = 0; q < 8; ++q) v[q] = (short)f2bf(tmp[q]);
    afrag[mt][0] = v;
    *(float4*)tmp = *(const float4*)(ep + 32);
    *(float4*)(tmp + 4) = *(const float4*)(ep + 36);
#pragma unroll
    for (int q = 0; q < 8; ++q) v[q] = (short)f2bf(tmp[q]);
    afrag[mt][1] = v;
  }
  float adjv[4][4];
#pragma unroll
  for (int mt = 0; mt < 4; ++mt)
#pragma unroll
    for (int r = 0; r < 4; ++r)
      adjv[mt][r] = adj[pbase + mt * 16 + lg * 4 + r];

  const float* u2r = u2 + ((size_t)(b * N_ + i)) * G_;

  for (int t = 0; t < 4; ++t) {  // e-group: outputs e = t*16 + lr
    f32x4 acc[6][4];
    f32x4 zero = {0.f, 0.f, 0.f, 0.f};
#pragma unroll
    for (int u = 0; u < 6; ++u)
#pragma unroll
      for (int mt = 0; mt < 4; ++mt) acc[u][mt] = zero;

#pragma unroll
    for (int s = 0; s < 2; ++s)
#pragma unroll
      for (int u = 0; u < 6; ++u) {
        int T = t + 4 * u;                    // N-tiles {t, t+4, ..., t+20}
        int rowb = T * 16 + lr;
        bf16x8 bfrag = *(const bf16x8*)(Bc + rowb * 128 +
                                        ((s * 64 + lg * 16) ^ ((rowb & 7) << 4)));
#pragma unroll
        for (int mt = 0; mt < 4; ++mt)
          acc[u][mt] = __builtin_amdgcn_mfma_f32_16x16x32_bf16(
              afrag[mt][s], bfrag, acc[u][mt], 0, 0, 0);
      }

    int e = t * 16 + lr;
    float u20 = u2r[e], u21 = u2r[e + 64], u22 = u2r[e + 128];
    float ub0 = ub[e], ub1 = ub[e + 64], ub2 = ub[e + 128];
    float bi0 = bih[e], bi1 = bih[e + 64], bi2 = bih[e + 128];
    float bh0 = bhh[e], bh1 = bhh[e + 64], bh2 = bhh[e + 128];
#pragma unroll
    for (int mt = 0; mt < 4; ++mt) {
#pragma unroll
      for (int r = 0; r < 4; ++r) {
        int prow = mt * 16 + lg * 4 + r;    // D row = pair within wave
        size_t pair = pbase + prow;
        const float* u1r = u1 + ((size_t)(b * N_ + j0 + prow)) * G_;
        float a = adjv[mt][r];
        float gir = a * (ub0 + u1r[e] + u20 + acc[0][mt][r]) + bi0;
        float giz = a * (ub1 + u1r[e + 64] + u21 + acc[1][mt][r]) + bi1;
        float gin = a * (ub2 + u1r[e + 128] + u22 + acc[2][mt][r]) + bi2;
        float ghr = acc[3][mt][r] + bh0;
        float ghz = acc[4][mt][r] + bh1;
        float ghn = acc[5][mt][r] + bh2;
        float rg = sigm(gir + ghr);
        float z = sigm(giz + ghz);
        float n = tanh_f(gin + rg * ghn);
        float ev = edge[pair * 64 + e];
        float y = (1.f - z) * n + z * ev;
        out[pair * 64 + e] = y * sigm(y);
      }
    }
  }
}

// ================= fallback fp32 path (used only if ws too small) =================
__global__ __launch_bounds__(64) void mkernelF(const float* __restrict__ edge,
                                               const float* __restrict__ adj,
                                               const float* __restrict__ Wlin,
                                               const float* __restrict__ blin,
                                               const float* __restrict__ h,
                                               float* __restrict__ mout) {
  size_t p = (size_t)blockIdx.x * 64 + threadIdx.x;
  int b = (int)(p >> 18), i = (int)((p >> 9) & 511), j = (int)(p & 511);
  float ed[E_], hj[E_], hi[E_];
  const float4* ep = (const float4*)(edge + p * E_);
  const float4* hjp = (const float4*)(h + ((size_t)(b * N_ + j)) * E_);
  const float4* hip = (const float4*)(h + ((size_t)(b * N_ + i)) * E_);
#pragma unroll
  for (int k = 0; k < E_ / 4; ++k) {
    float4 v = ep[k];
    ed[4 * k] = v.x; ed[4 * k + 1] = v.y; ed[4 * k + 2] = v.z; ed[4 * k + 3] = v.w;
    float4 a = hjp[k];
    hj[4 * k] = a.x; hj[4 * k + 1] = a.y; hj[4 * k + 2] = a.z; hj[4 * k + 3] = a.w;
    float4 u = hip[k];
    hi[4 * k] = u.x; hi[4 * k + 1] = u.y; hi[4 * k + 2] = u.z; hi[4 * k + 3] = u.w;
  }
  float av = adj[p];
  float* mo = mout + p * E_;
  for (int e = 0; e < E_; ++e) {
    const float* w = Wlin + e * LIN_IN_;
    float acc = blin[e];
#pragma unroll
    for (int k = 0; k < E_; ++k)
      acc += hj[k] * w[k] + ed[k] * w[64 + k] + hi[k] * w[128 + k];
    mo[e] = av * acc;
  }
}
__global__ __launch_bounds__(64) void gkernelF(const float* __restrict__ edge,
                                               const float* mbuf,
                                               const float* __restrict__ wih,
                                               const float* __restrict__ whh,
                                               const float* __restrict__ bih,
                                               const float* __restrict__ bhh,
                                               float* out) {
  size_t p = (size_t)blockIdx.x * 64 + threadIdx.x;
  float ed[E_], m[E_];
  const float4* ep = (const float4*)(edge + p * E_);
  const float4* mp = (const float4*)(mbuf + p * E_);
#pragma unroll
  for (int k = 0; k < E_ / 4; ++k) {
    float4 v = ep[k];
    ed[4 * k] = v.x; ed[4 * k + 1] = v.y; ed[4 * k + 2] = v.z; ed[4 * k + 3] = v.w;
    float4 u = mp[k];
    m[4 * k] = u.x; m[4 * k + 1] = u.y; m[4 * k + 2] = u.z; m[4 * k + 3] = u.w;
  }
  float* op = out + p * E_;
  for (int e = 0; e < E_; ++e) {
    const float* wr = wih + e * 64;
    const float* wz = wih + (64 + e) * 64;
    const float* wn = wih + (128 + e) * 64;
    const float* vr = whh + e * 64;
    const float* vz = whh + (64 + e) * 64;
    const float* vn = whh + (128 + e) * 64;
    float ir = bih[e], iz = bih[64 + e], inn = bih[128 + e];
    float hr = bhh[e], hz = bhh[64 + e], hn = bhh[128 + e];
#pragma unroll
    for (int k = 0; k < E_; ++k) {
      float mk = m[k], ek = ed[k];
      ir += mk * wr[k]; iz += mk * wz[k]; inn += mk * wn[k];
      hr += ek * vr[k]; hz += ek * vz[k]; hn += ek * vn[k];
    }
    float r = sigm(ir + hr);
    float z = sigm(iz + hz);
    float nv = tanh_f(inn + r * hn);
    float nh = (1.f - z) * nv + z * ed[e];
    op[e] = nh * sigm(nh);
  }
}

extern "C" void kernel_launch(void* const* d_in, const int* in_sizes, int n_in,
                              void* d_out, int out_size, void* d_ws, size_t ws_size,
                              hipStream_t stream) {
  const float* h    = (const float*)d_in[0];
  const float* edge = (const float*)d_in[1];
  const float* adj  = (const float*)d_in[2];
  const float* Wlin = (const float*)d_in[3];
  const float* blin = (const float*)d_in[4];
  const float* wih  = (const float*)d_in[5];
  const float* whh  = (const float*)d_in[6];
  const float* bih  = (const float*)d_in[7];
  const float* bhh  = (const float*)d_in[8];
  float* out = (float*)d_out;

  // ws layout (bytes): Bt bf16 49152 | u1 786432 | u2 786432 | V1 49152 | V2 49152 | ub 768
  const size_t WS_NEEDED = 49152 + 2 * 786432 + 2 * 49152 + 768;
  if (ws_size >= WS_NEEDED) {
    char* w = (char*)d_ws;
    unsigned short* Bt = (unsigned short*)w;
    float* u1 = (float*)(w + 49152);
    float* u2 = (float*)(w + 49152 + 786432);
    float* V1 = (float*)(w + 49152 + 2 * 786432);
    float* V2 = (float*)(w + 49152 + 2 * 786432 + 49152);
    float* ub = (float*)(w + 49152 + 2 * 786432 + 2 * 49152);
    prep1<<<384, 64, 0, stream>>>(Wlin, blin, wih, whh, Bt, V1, V2, ub);
    prep2<<<B_ * N_, 192, 0, stream>>>(h, V1, V2, u1, u2);
    fused<<<(B_ * N_ * N_) / 256, 256, 0, stream>>>(edge, adj, Bt, u1, u2, ub,
                                                    bih, bhh, out);
  } else {
    size_t npairs = (size_t)B_ * N_ * N_;
    int blocks = (int)(npairs / 64);
    mkernelF<<<blocks, 64, 0, stream>>>(edge, adj, Wlin, blin, h, out);
    gkernelF<<<blocks, 64, 0, stream>>>(edge, out, wih, whh, bih, bhh, out);
  }
}